// Round 8
// baseline (1030.571 us; speedup 1.0000x reference)
//
#include <hip/hip_runtime.h>

#define NVAR 1000000
#define NCON 500000
#define HFE 10
#define EPB 8192     // edges per pass-A block
#define KB_CAP 12288 // kB staging capacity (bucket avg 8192, sd ~90)

// ============================================================================
// Radix (atomic-free) CSR build with rank-then-emit coalesced writes
// ============================================================================

__global__ __launch_bounds__(256) void kA_hist(const int* __restrict__ keys,
                                               unsigned int* __restrict__ bhist,
                                               int ne, int shift, int nblk) {
    __shared__ unsigned int h[1024];
    int tid = threadIdx.x, b = blockIdx.x;
    for (int t = tid; t < 1024; t += 256) h[t] = 0;
    __syncthreads();
    int beg = b * EPB, end = min(ne, beg + EPB);
    for (int e = beg + tid; e < end; e += 256) atomicAdd(&h[keys[e] >> shift], 1u);
    __syncthreads();
    for (int t = tid; t < 1024; t += 256) bhist[(size_t)t * nblk + b] = h[t];
}

// rank-then-emit scatter: writes to `bucketed` walk segments in order
__global__ __launch_bounds__(256) void kA_scat(const int* __restrict__ keys,
                                               const int* __restrict__ vals,
                                               const float* __restrict__ w,
                                               const unsigned int* __restrict__ scanned,
                                               int2* __restrict__ bucketed,
                                               int ne, int shift, int nblk) {
    __shared__ unsigned int h[1024];    // histogram, then rank cursor
    __shared__ unsigned int lb[1024];   // local exclusive base
    __shared__ unsigned int gb[1024];   // global segment base
    __shared__ unsigned int sc[256];
    __shared__ unsigned short lidx[EPB];
    int tid = threadIdx.x, b = blockIdx.x;
    for (int t = tid; t < 1024; t += 256) {
        h[t] = 0;
        gb[t] = scanned[(size_t)t * nblk + b];
    }
    __syncthreads();
    int beg = b * EPB, end = min(ne, beg + EPB), cnt = end - beg;
    // phase 0: local histogram
    for (int i = tid; i < cnt; i += 256) atomicAdd(&h[keys[beg + i] >> shift], 1u);
    __syncthreads();
    // exclusive scan h -> lb (4/thread + Hillis-Steele over 256 partials)
    unsigned v0, v1, v2, v3;
    int q = tid * 4;
    v0 = h[q]; v1 = h[q + 1]; v2 = h[q + 2]; v3 = h[q + 3];
    sc[tid] = v0 + v1 + v2 + v3;
    __syncthreads();
    for (int dd = 1; dd < 256; dd <<= 1) {
        unsigned add = (tid >= dd) ? sc[tid - dd] : 0u;
        __syncthreads();
        sc[tid] += add;
        __syncthreads();
    }
    unsigned ex = (tid == 0) ? 0u : sc[tid - 1];
    lb[q]     = ex;
    lb[q + 1] = ex + v0;
    lb[q + 2] = ex + v0 + v1;
    lb[q + 3] = ex + v0 + v1 + v2;
    __syncthreads();
    // reset rank cursors
    for (int t = tid; t < 1024; t += 256) h[t] = 0;
    __syncthreads();
    // phase 1: rank each edge, record permutation
    for (int i = tid; i < cnt; i += 256) {
        unsigned bkt = (unsigned)keys[beg + i] >> shift;
        unsigned r = atomicAdd(&h[bkt], 1u);
        lidx[lb[bkt] + r] = (unsigned short)i;
    }
    __syncthreads();
    // phase 2: emit in sorted order -> coalesced segment runs
    unsigned mask = (1u << shift) - 1u;
    for (int i = tid; i < cnt; i += 256) {
        int e = beg + (int)lidx[i];
        int k = keys[e];
        unsigned bkt = (unsigned)k >> shift;
        unsigned dst = gb[bkt] + ((unsigned)i - lb[bkt]);
        bucketed[dst] = make_int2(__float_as_int(w[e]),
                                  (vals[e] << shift) | (unsigned)(k & (int)mask));
    }
}

// per-bucket: histogram low bits -> deg/start; rank-then-emit -> coalesced csr
__global__ __launch_bounds__(256) void kB(const int2* __restrict__ bucketed,
                                          const unsigned int* __restrict__ scanned,
                                          unsigned int* __restrict__ deg,
                                          unsigned int* __restrict__ start,
                                          int2* __restrict__ csr,
                                          int nnodes, int shift, int nblk) {
    __shared__ unsigned int h[1024], s[1024], cr[1024], sc[256];
    __shared__ unsigned short lidx[KB_CAP];
    const int W = 1 << shift;
    const unsigned mask = (unsigned)(W - 1);
    int d = blockIdx.x, tid = threadIdx.x;
    unsigned base = scanned[(size_t)d * nblk];
    unsigned next = scanned[(size_t)(d + 1) * nblk];
    int bsz = (int)(next - base);
    for (int t = tid; t < W; t += 256) { h[t] = 0; cr[t] = 0; }
    __syncthreads();
    for (int i = tid; i < bsz; i += 256)
        atomicAdd(&h[(unsigned)bucketed[base + i].y & mask], 1u);  // LDS atomic
    __syncthreads();
    // exclusive scan h[0..W) -> s
    unsigned v0 = 0, v1 = 0, v2 = 0, v3 = 0;
    int q = tid * 4;
    if (q < W) { v0 = h[q]; v1 = h[q + 1]; v2 = h[q + 2]; v3 = h[q + 3]; }
    sc[tid] = v0 + v1 + v2 + v3;
    __syncthreads();
    for (int dd = 1; dd < 256; dd <<= 1) {
        unsigned add = (tid >= dd) ? sc[tid - dd] : 0u;
        __syncthreads();
        sc[tid] += add;
        __syncthreads();
    }
    unsigned e = (tid == 0) ? 0u : sc[tid - 1];
    if (q < W) {
        s[q]     = e;
        s[q + 1] = e + v0;
        s[q + 2] = e + v0 + v1;
        s[q + 3] = e + v0 + v1 + v2;
    }
    __syncthreads();
    int lo = d << shift;
    for (int t = tid; t < W; t += 256) {
        int node = lo + t;
        if (node < nnodes) { deg[node] = h[t]; start[node] = base + s[t]; }
    }
    __syncthreads();
    if (bsz <= KB_CAP) {
        // rank phase: record permutation within bucket
        for (int i = tid; i < bsz; i += 256) {
            unsigned low = (unsigned)bucketed[base + i].y & mask;
            unsigned r = atomicAdd(&cr[low], 1u);
            lidx[s[low] + r] = (unsigned short)i;
        }
        __syncthreads();
        // emit phase: csr[base + j] for consecutive j -> fully coalesced
        for (int j = tid; j < bsz; j += 256) {
            int2 p = bucketed[base + (int)lidx[j]];
            csr[base + j] = make_int2(p.y >> shift, p.x);
        }
    } else {
        // safety fallback: scattered write (statistically unreachable)
        for (int i = tid; i < bsz; i += 256) {
            int2 p = bucketed[base + i];
            unsigned low = (unsigned)p.y & mask;
            unsigned pos = base + s[low] + atomicAdd(&cr[low], 1u);
            csr[pos] = make_int2(p.y >> shift, p.x);
        }
    }
}

__global__ __launch_bounds__(256) void k_scan_blocks(const unsigned int* __restrict__ in,
                                                     unsigned int* __restrict__ out,
                                                     unsigned int* __restrict__ bsum,
                                                     int n) {
    __shared__ unsigned int sT[256];
    int base = blockIdx.x * 1024 + threadIdx.x * 4;
    unsigned int v0 = 0, v1 = 0, v2 = 0, v3 = 0;
    if (base + 3 < n) {
        uint4 u = *(const uint4*)(in + base);
        v0 = u.x; v1 = u.y; v2 = u.z; v3 = u.w;
    } else {
        if (base     < n) v0 = in[base];
        if (base + 1 < n) v1 = in[base + 1];
        if (base + 2 < n) v2 = in[base + 2];
        if (base + 3 < n) v3 = in[base + 3];
    }
    sT[threadIdx.x] = v0 + v1 + v2 + v3;
    __syncthreads();
    for (int d = 1; d < 256; d <<= 1) {
        unsigned int add = (threadIdx.x >= (unsigned)d) ? sT[threadIdx.x - d] : 0u;
        __syncthreads();
        sT[threadIdx.x] += add;
        __syncthreads();
    }
    unsigned int excl = (threadIdx.x == 0) ? 0u : sT[threadIdx.x - 1];
    if (base     < n) out[base]     = excl;
    if (base + 1 < n) out[base + 1] = excl + v0;
    if (base + 2 < n) out[base + 2] = excl + v0 + v1;
    if (base + 3 < n) out[base + 3] = excl + v0 + v1 + v2;
    if (threadIdx.x == 255 && bsum) bsum[blockIdx.x] = sT[255];
}

__global__ __launch_bounds__(256) void k_scan_add(unsigned int* __restrict__ data,
                                                  const unsigned int* __restrict__ bscan,
                                                  int n) {
    int base = blockIdx.x * 1024 + threadIdx.x * 4;
    unsigned int add = bscan[blockIdx.x];
    if (base + 3 < n) {
        uint4 u = *(const uint4*)(data + base);
        u.x += add; u.y += add; u.z += add; u.w += add;
        *(uint4*)(data + base) = u;
    } else {
        if (base     < n) data[base]     += add;
        if (base + 1 < n) data[base + 1] += add;
        if (base + 2 < n) data[base + 2] += add;
        if (base + 3 < n) data[base + 3] += add;
    }
}

__global__ __launch_bounds__(256) void k_out(const double* __restrict__ partials, int np,
                                             float* __restrict__ out) {
    __shared__ double red[256];
    double a = 0.0;
    for (int i = threadIdx.x; i < np; i += blockDim.x) a += partials[i];
    red[threadIdx.x] = a;
    __syncthreads();
    for (int off = 128; off > 0; off >>= 1) {
        if (threadIdx.x < off) red[threadIdx.x] += red[threadIdx.x + off];
        __syncthreads();
    }
    if (threadIdx.x == 0) out[0] = (float)(red[0] / (double)NVAR);
}

// ============================================================================
// PADDED node pipeline: 64 B feature rows, quad-per-node gathers, 4-edge unroll
// ============================================================================

__global__ __launch_bounds__(256) void k_xvar_p(const float* __restrict__ var_c,
                                                const float* __restrict__ var_x,
                                                const unsigned int* __restrict__ deg_var,
                                                const float* __restrict__ Wv,
                                                const float* __restrict__ bv,
                                                float* __restrict__ Xs, int n) {
    int i = blockIdx.x * blockDim.x + threadIdx.x;
    if (i >= n) return;
    float c = var_c[i], x = var_x[i];
    float rs = rsqrtf(fmaxf((float)deg_var[i], 1.0f));
    float o[16];
#pragma unroll
    for (int j = 0; j < HFE; j++) {
        float t = fmaf(c, Wv[j], fmaf(x, Wv[HFE + j], bv[j]));
        o[j] = fmaxf(t, 0.0f) * rs;
    }
#pragma unroll
    for (int j = HFE; j < 16; j++) o[j] = 0.0f;
    float4* dst4 = (float4*)(Xs + (size_t)i * 16);
#pragma unroll
    for (int j = 0; j < 4; j++)
        dst4[j] = make_float4(o[4 * j], o[4 * j + 1], o[4 * j + 2], o[4 * j + 3]);
}

__global__ __launch_bounds__(256) void k_gq_con(const int2* __restrict__ csr,
                                                const unsigned int* __restrict__ start,
                                                const unsigned int* __restrict__ deg,
                                                const float* __restrict__ feat,  // [N][16]
                                                const float* __restrict__ W2,
                                                const float* __restrict__ b2,
                                                float* __restrict__ hs, int n) { // [n][16]
    __shared__ float sW[100], sb[10];
    for (int t = threadIdx.x; t < 100; t += blockDim.x) sW[t] = W2[t];
    if (threadIdx.x < 10) sb[threadIdx.x] = b2[threadIdx.x];
    __syncthreads();
    int t = blockIdx.x * blockDim.x + threadIdx.x;
    int quad = t >> 2, lane = t & 3;
    if (quad >= n) return;
    unsigned beg = start[quad], cnt = deg[quad], end = beg + cnt;
    float4 acc = make_float4(0.f, 0.f, 0.f, 0.f);
    unsigned p = beg;
    for (; p + 4 <= end; p += 4) {
        int2 e0 = csr[p];
        int2 e1 = csr[p + 1];
        int2 e2 = csr[p + 2];
        int2 e3 = csr[p + 3];
        float4 v0 = *(const float4*)(feat + (size_t)e0.x * 16 + lane * 4);
        float4 v1 = *(const float4*)(feat + (size_t)e1.x * 16 + lane * 4);
        float4 v2 = *(const float4*)(feat + (size_t)e2.x * 16 + lane * 4);
        float4 v3 = *(const float4*)(feat + (size_t)e3.x * 16 + lane * 4);
        float w0 = __int_as_float(e0.y), w1 = __int_as_float(e1.y);
        float w2 = __int_as_float(e2.y), w3 = __int_as_float(e3.y);
        acc.x = fmaf(w0, v0.x, acc.x); acc.y = fmaf(w0, v0.y, acc.y);
        acc.z = fmaf(w0, v0.z, acc.z); acc.w = fmaf(w0, v0.w, acc.w);
        acc.x = fmaf(w1, v1.x, acc.x); acc.y = fmaf(w1, v1.y, acc.y);
        acc.z = fmaf(w1, v1.z, acc.z); acc.w = fmaf(w1, v1.w, acc.w);
        acc.x = fmaf(w2, v2.x, acc.x); acc.y = fmaf(w2, v2.y, acc.y);
        acc.z = fmaf(w2, v2.z, acc.z); acc.w = fmaf(w2, v2.w, acc.w);
        acc.x = fmaf(w3, v3.x, acc.x); acc.y = fmaf(w3, v3.y, acc.y);
        acc.z = fmaf(w3, v3.z, acc.z); acc.w = fmaf(w3, v3.w, acc.w);
    }
    for (; p < end; ++p) {
        int2 e = csr[p];
        float we = __int_as_float(e.y);
        float4 v = *(const float4*)(feat + (size_t)e.x * 16 + lane * 4);
        acc.x = fmaf(we, v.x, acc.x);
        acc.y = fmaf(we, v.y, acc.y);
        acc.z = fmaf(we, v.z, acc.z);
        acc.w = fmaf(we, v.w, acc.w);
    }
    float rs = rsqrtf(fmaxf((float)cnt, 1.0f));
    float a[10];
    a[0] = __shfl(acc.x, 0, 4); a[1] = __shfl(acc.y, 0, 4);
    a[2] = __shfl(acc.z, 0, 4); a[3] = __shfl(acc.w, 0, 4);
    a[4] = __shfl(acc.x, 1, 4); a[5] = __shfl(acc.y, 1, 4);
    a[6] = __shfl(acc.z, 1, 4); a[7] = __shfl(acc.w, 1, 4);
    a[8] = __shfl(acc.x, 2, 4); a[9] = __shfl(acc.y, 2, 4);
#pragma unroll
    for (int j = 0; j < 10; j++) a[j] *= rs;
    float o[12];
#pragma unroll
    for (int k = 0; k < 10; k++) {
        float s2 = sb[k];
#pragma unroll
        for (int j = 0; j < 10; j++) s2 = fmaf(a[j], sW[j * 10 + k], s2);
        o[k] = fmaxf(s2, 0.0f) * rs;   // relu + prescale for conv2
    }
    o[10] = 0.0f; o[11] = 0.0f;
    float4 wv = (lane < 3) ? make_float4(o[lane * 4], o[lane * 4 + 1],
                                         o[lane * 4 + 2], o[lane * 4 + 3])
                           : make_float4(0.f, 0.f, 0.f, 0.f);
    *(float4*)(hs + (size_t)quad * 16 + lane * 4) = wv;
}

__global__ __launch_bounds__(256) void k_gq_final(const int2* __restrict__ csr,
                                                  const unsigned int* __restrict__ start,
                                                  const unsigned int* __restrict__ deg,
                                                  const float* __restrict__ feat, // [NCON][16]
                                                  const float* __restrict__ W2,
                                                  const float* __restrict__ b2,
                                                  const float* __restrict__ Wo1,
                                                  const float* __restrict__ bo1,
                                                  const float* __restrict__ Wo2,
                                                  const float* __restrict__ bo2,
                                                  const float* __restrict__ Wo3,
                                                  const float* __restrict__ bo3,
                                                  double* __restrict__ partials, int n) {
    __shared__ float sW2[100], sb2[10], sWo1[100], sbo1[10], sWo2[100], sbo2[10], sWo3[10], sbo3;
    for (int t = threadIdx.x; t < 100; t += blockDim.x) {
        sW2[t] = W2[t]; sWo1[t] = Wo1[t]; sWo2[t] = Wo2[t];
    }
    if (threadIdx.x < 10) {
        sb2[threadIdx.x]  = b2[threadIdx.x];
        sbo1[threadIdx.x] = bo1[threadIdx.x];
        sbo2[threadIdx.x] = bo2[threadIdx.x];
        sWo3[threadIdx.x] = Wo3[threadIdx.x];
    }
    if (threadIdx.x == 0) sbo3 = bo3[0];
    __syncthreads();

    int t = blockIdx.x * blockDim.x + threadIdx.x;
    int quad = t >> 2, lane = t & 3;
    double accd = 0.0;
    if (quad < n) {
        unsigned beg = start[quad], cnt = deg[quad], end = beg + cnt;
        float4 acc = make_float4(0.f, 0.f, 0.f, 0.f);
        unsigned p = beg;
        for (; p + 4 <= end; p += 4) {
            int2 e0 = csr[p];
            int2 e1 = csr[p + 1];
            int2 e2 = csr[p + 2];
            int2 e3 = csr[p + 3];
            float4 v0 = *(const float4*)(feat + (size_t)e0.x * 16 + lane * 4);
            float4 v1 = *(const float4*)(feat + (size_t)e1.x * 16 + lane * 4);
            float4 v2 = *(const float4*)(feat + (size_t)e2.x * 16 + lane * 4);
            float4 v3 = *(const float4*)(feat + (size_t)e3.x * 16 + lane * 4);
            float w0 = __int_as_float(e0.y), w1 = __int_as_float(e1.y);
            float w2 = __int_as_float(e2.y), w3 = __int_as_float(e3.y);
            acc.x = fmaf(w0, v0.x, acc.x); acc.y = fmaf(w0, v0.y, acc.y);
            acc.z = fmaf(w0, v0.z, acc.z); acc.w = fmaf(w0, v0.w, acc.w);
            acc.x = fmaf(w1, v1.x, acc.x); acc.y = fmaf(w1, v1.y, acc.y);
            acc.z = fmaf(w1, v1.z, acc.z); acc.w = fmaf(w1, v1.w, acc.w);
            acc.x = fmaf(w2, v2.x, acc.x); acc.y = fmaf(w2, v2.y, acc.y);
            acc.z = fmaf(w2, v2.z, acc.z); acc.w = fmaf(w2, v2.w, acc.w);
            acc.x = fmaf(w3, v3.x, acc.x); acc.y = fmaf(w3, v3.y, acc.y);
            acc.z = fmaf(w3, v3.z, acc.z); acc.w = fmaf(w3, v3.w, acc.w);
        }
        for (; p < end; ++p) {
            int2 e = csr[p];
            float we = __int_as_float(e.y);
            float4 v = *(const float4*)(feat + (size_t)e.x * 16 + lane * 4);
            acc.x = fmaf(we, v.x, acc.x);
            acc.y = fmaf(we, v.y, acc.y);
            acc.z = fmaf(we, v.z, acc.z);
            acc.w = fmaf(we, v.w, acc.w);
        }
        float rs = rsqrtf(fmaxf((float)cnt, 1.0f));
        float a[10];
        a[0] = __shfl(acc.x, 0, 4); a[1] = __shfl(acc.y, 0, 4);
        a[2] = __shfl(acc.z, 0, 4); a[3] = __shfl(acc.w, 0, 4);
        a[4] = __shfl(acc.x, 1, 4); a[5] = __shfl(acc.y, 1, 4);
        a[6] = __shfl(acc.z, 1, 4); a[7] = __shfl(acc.w, 1, 4);
        a[8] = __shfl(acc.x, 2, 4); a[9] = __shfl(acc.y, 2, 4);
#pragma unroll
        for (int j = 0; j < 10; j++) a[j] *= rs;
        float h[10], z[10];
#pragma unroll
        for (int k = 0; k < 10; k++) {
            float s2 = sb2[k];
#pragma unroll
            for (int j = 0; j < 10; j++) s2 = fmaf(a[j], sW2[j * 10 + k], s2);
            h[k] = fmaxf(s2, 0.0f);
        }
#pragma unroll
        for (int k = 0; k < 10; k++) {
            float s2 = sbo1[k];
#pragma unroll
            for (int j = 0; j < 10; j++) s2 = fmaf(h[j], sWo1[j * 10 + k], s2);
            z[k] = fmaxf(s2, 0.0f);
        }
        float t3 = sbo3;
#pragma unroll
        for (int k = 0; k < 10; k++) {
            float s2 = sbo2[k];
#pragma unroll
            for (int j = 0; j < 10; j++) s2 = fmaf(z[j], sWo2[j * 10 + k], s2);
            s2 = fmaxf(s2, 0.0f);
            t3 = fmaf(s2, sWo3[k], t3);
        }
        if (lane == 0) accd = (double)t3;   // lanes 1-3 hold identical t3
    }

    __shared__ double red[256];
    red[threadIdx.x] = accd;
    __syncthreads();
    for (int off = blockDim.x / 2; off > 0; off >>= 1) {
        if (threadIdx.x < off) red[threadIdx.x] += red[threadIdx.x + off];
        __syncthreads();
    }
    if (threadIdx.x == 0) partials[blockIdx.x] = red[0];
}

// ============================================================================
// FALLBACK node kernels (unpadded): only used if ws too small for padded path
// ============================================================================

__global__ __launch_bounds__(256) void k_xvar(const float* __restrict__ var_c,
                                              const float* __restrict__ var_x,
                                              const unsigned int* __restrict__ deg_var,
                                              const float* __restrict__ Wv,
                                              const float* __restrict__ bv,
                                              float* __restrict__ Xs, int n) {
    int i = blockIdx.x * blockDim.x + threadIdx.x;
    if (i >= n) return;
    float c = var_c[i], x = var_x[i];
    float rs = rsqrtf(fmaxf((float)deg_var[i], 1.0f));
    float o[HFE];
#pragma unroll
    for (int j = 0; j < HFE; j++) {
        float t = fmaf(c, Wv[j], fmaf(x, Wv[HFE + j], bv[j]));
        o[j] = fmaxf(t, 0.0f) * rs;
    }
    float2* dst2 = (float2*)(Xs + (size_t)i * HFE);
#pragma unroll
    for (int j = 0; j < 5; j++) dst2[j] = make_float2(o[2 * j], o[2 * j + 1]);
}

__global__ __launch_bounds__(256) void k_gather_con(const int2* __restrict__ csr,
                                                    const unsigned int* __restrict__ start,
                                                    const unsigned int* __restrict__ deg,
                                                    const float* __restrict__ feat,
                                                    const float* __restrict__ W2,
                                                    const float* __restrict__ b2,
                                                    float* __restrict__ hs, int n) {
    __shared__ float sW[100], sb[10];
    for (int t = threadIdx.x; t < 100; t += blockDim.x) sW[t] = W2[t];
    if (threadIdx.x < 10) sb[threadIdx.x] = b2[threadIdx.x];
    __syncthreads();
    int i = blockIdx.x * blockDim.x + threadIdx.x;
    if (i >= n) return;
    unsigned int beg = start[i], cnt = deg[i], end = beg + cnt;
    float acc[HFE];
#pragma unroll
    for (int j = 0; j < HFE; j++) acc[j] = 0.0f;
    for (unsigned int p = beg; p < end; ++p) {
        int2 t = csr[p];
        float we = __int_as_float(t.y);
        const float2* row = (const float2*)(feat + (size_t)t.x * HFE);
#pragma unroll
        for (int j = 0; j < 5; j++) {
            float2 v = row[j];
            acc[2 * j]     = fmaf(we, v.x, acc[2 * j]);
            acc[2 * j + 1] = fmaf(we, v.y, acc[2 * j + 1]);
        }
    }
    float rs = rsqrtf(fmaxf((float)cnt, 1.0f));
#pragma unroll
    for (int j = 0; j < HFE; j++) acc[j] *= rs;
    float o[HFE];
#pragma unroll
    for (int k = 0; k < HFE; k++) {
        float t = sb[k];
#pragma unroll
        for (int j = 0; j < HFE; j++) t = fmaf(acc[j], sW[j * HFE + k], t);
        o[k] = fmaxf(t, 0.0f) * rs;
    }
    float2* dst2 = (float2*)(hs + (size_t)i * HFE);
#pragma unroll
    for (int j = 0; j < 5; j++) dst2[j] = make_float2(o[2 * j], o[2 * j + 1]);
}

__global__ __launch_bounds__(256) void k_gather_final(const int2* __restrict__ csr,
                                                      const unsigned int* __restrict__ start,
                                                      const unsigned int* __restrict__ deg,
                                                      const float* __restrict__ feat,
                                                      const float* __restrict__ W2,
                                                      const float* __restrict__ b2,
                                                      const float* __restrict__ Wo1,
                                                      const float* __restrict__ bo1,
                                                      const float* __restrict__ Wo2,
                                                      const float* __restrict__ bo2,
                                                      const float* __restrict__ Wo3,
                                                      const float* __restrict__ bo3,
                                                      double* __restrict__ partials, int n) {
    __shared__ float sW2[100], sb2[10], sWo1[100], sbo1[10], sWo2[100], sbo2[10], sWo3[10], sbo3;
    for (int t = threadIdx.x; t < 100; t += blockDim.x) {
        sW2[t] = W2[t]; sWo1[t] = Wo1[t]; sWo2[t] = Wo2[t];
    }
    if (threadIdx.x < 10) {
        sb2[threadIdx.x]  = b2[threadIdx.x];
        sbo1[threadIdx.x] = bo1[threadIdx.x];
        sbo2[threadIdx.x] = bo2[threadIdx.x];
        sWo3[threadIdx.x] = Wo3[threadIdx.x];
    }
    if (threadIdx.x == 0) sbo3 = bo3[0];
    __syncthreads();

    double accd = 0.0;
    int i = blockIdx.x * blockDim.x + threadIdx.x;
    if (i < n) {
        unsigned int beg = start[i], cnt = deg[i], end = beg + cnt;
        float acc[HFE];
#pragma unroll
        for (int j = 0; j < HFE; j++) acc[j] = 0.0f;
        for (unsigned int p = beg; p < end; ++p) {
            int2 t = csr[p];
            float we = __int_as_float(t.y);
            const float2* row = (const float2*)(feat + (size_t)t.x * HFE);
#pragma unroll
            for (int j = 0; j < 5; j++) {
                float2 v = row[j];
                acc[2 * j]     = fmaf(we, v.x, acc[2 * j]);
                acc[2 * j + 1] = fmaf(we, v.y, acc[2 * j + 1]);
            }
        }
        float rs = rsqrtf(fmaxf((float)cnt, 1.0f));
#pragma unroll
        for (int j = 0; j < HFE; j++) acc[j] *= rs;
        float h[HFE], z[HFE];
#pragma unroll
        for (int k = 0; k < HFE; k++) {
            float t = sb2[k];
#pragma unroll
            for (int j = 0; j < HFE; j++) t = fmaf(acc[j], sW2[j * HFE + k], t);
            h[k] = fmaxf(t, 0.0f);
        }
#pragma unroll
        for (int k = 0; k < HFE; k++) {
            float t = sbo1[k];
#pragma unroll
            for (int j = 0; j < HFE; j++) t = fmaf(h[j], sWo1[j * HFE + k], t);
            z[k] = fmaxf(t, 0.0f);
        }
        float t3 = sbo3;
#pragma unroll
        for (int k = 0; k < HFE; k++) {
            float t = sbo2[k];
#pragma unroll
            for (int j = 0; j < HFE; j++) t = fmaf(z[j], sWo2[j * HFE + k], t);
            t = fmaxf(t, 0.0f);
            t3 = fmaf(t, sWo3[k], t3);
        }
        accd = (double)t3;
    }

    __shared__ double red[256];
    red[threadIdx.x] = accd;
    __syncthreads();
    for (int off = blockDim.x / 2; off > 0; off >>= 1) {
        if (threadIdx.x < off) red[threadIdx.x] += red[threadIdx.x + off];
        __syncthreads();
    }
    if (threadIdx.x == 0) partials[blockIdx.x] = red[0];
}

// ============================================================================
// Launch
// ============================================================================

extern "C" void kernel_launch(void* const* d_in, const int* in_sizes, int n_in,
                              void* d_out, int out_size, void* d_ws, size_t ws_size,
                              hipStream_t stream) {
    const float* var_c  = (const float*)d_in[0];
    const float* var_x  = (const float*)d_in[1];
    const int*   e_src  = (const int*)d_in[3];
    const int*   e_dst  = (const int*)d_in[4];
    const float* e_w    = (const float*)d_in[5];
    const float* Wv     = (const float*)d_in[6];
    const float* bv     = (const float*)d_in[7];
    const float* W2     = (const float*)d_in[12];
    const float* b2     = (const float*)d_in[13];
    const float* Wo1    = (const float*)d_in[14];
    const float* bo1    = (const float*)d_in[15];
    const float* Wo2    = (const float*)d_in[16];
    const float* bo2    = (const float*)d_in[17];
    const float* Wo3    = (const float*)d_in[18];
    const float* bo3    = (const float*)d_in[19];
    float* out = (float*)d_out;
    const int ne = in_sizes[3];
    (void)n_in; (void)out_size;

    const int B = 256;
    const int nblkA = (ne + EPB - 1) / EPB;     // 977
    const int scanN = 1024 * nblkA;
    const int NBs   = (scanN + 1023) / 1024;
    const int BKV   = (NVAR + 1023) >> 10;      // shift 10
    const int BKC   = (NCON + 511) >> 9;        // shift 9

    char* ws = (char*)d_ws;
    size_t off = 0;
    auto walloc = [&](size_t bytes) {
        void* p = ws + off;
        off = (off + bytes + 255) & ~(size_t)255;
        return p;
    };

    // ---- padded-path layout ----
    const int NFQ = (4 * NVAR + B - 1) / B;     // 15625 partials (quad final)
    int2*          csrV     = (int2*)walloc((size_t)ne * 8);             // 64 MB
    int2*          csrC     = (int2*)walloc((size_t)ne * 8);             // 64 MB
    int2*          bucketed = (int2*)walloc((size_t)ne * 8);             // 64 MB
    unsigned int*  bhist    = (unsigned int*)walloc((size_t)scanN * 4);  //  4 MB
    unsigned int*  scanned  = (unsigned int*)walloc((size_t)scanN * 4);  //  4 MB
    unsigned int*  deg_var  = (unsigned int*)walloc((size_t)NVAR * 4);
    unsigned int*  start_var= (unsigned int*)walloc((size_t)NVAR * 4);
    unsigned int*  deg_con  = (unsigned int*)walloc((size_t)NCON * 4);
    unsigned int*  start_con= (unsigned int*)walloc((size_t)NCON * 4);
    unsigned int*  bsum     = (unsigned int*)walloc(4096);
    unsigned int*  bscan    = (unsigned int*)walloc(4096);
    unsigned int*  bdummy   = (unsigned int*)walloc(256);
    double*        partials = (double*)walloc((size_t)NFQ * 8 + 64);
    float*         hs64     = (float*)walloc((size_t)NCON * 16 * 4);     // 32 MB
    size_t need_padded = off;
    float* Xs64 = (float*)bucketed;    // 64 MB overlay: bucketed dead after sortC

    if (ws_size >= need_padded) {
        // ---- sort V (key = src, shift 10) ----
        kA_hist<<<nblkA, B, 0, stream>>>(e_src, bhist, ne, 10, nblkA);
        k_scan_blocks<<<NBs, B, 0, stream>>>(bhist, scanned, bsum, scanN);
        k_scan_blocks<<<1,   B, 0, stream>>>(bsum, bscan, bdummy, NBs);
        k_scan_add   <<<NBs, B, 0, stream>>>(scanned, bscan, scanN);
        kA_scat<<<nblkA, B, 0, stream>>>(e_src, e_dst, e_w, scanned, bucketed, ne, 10, nblkA);
        kB<<<BKV, B, 0, stream>>>(bucketed, scanned, deg_var, start_var, csrV, NVAR, 10, nblkA);
        // ---- sort C (key = dst, shift 9) ----
        kA_hist<<<nblkA, B, 0, stream>>>(e_dst, bhist, ne, 9, nblkA);
        k_scan_blocks<<<NBs, B, 0, stream>>>(bhist, scanned, bsum, scanN);
        k_scan_blocks<<<1,   B, 0, stream>>>(bsum, bscan, bdummy, NBs);
        k_scan_add   <<<NBs, B, 0, stream>>>(scanned, bscan, scanN);
        kA_scat<<<nblkA, B, 0, stream>>>(e_dst, e_src, e_w, scanned, bucketed, ne, 9, nblkA);
        kB<<<BKC, B, 0, stream>>>(bucketed, scanned, deg_con, start_con, csrC, NCON, 9, nblkA);
        // ---- node pipeline (padded rows, quad gathers, unrolled) ----
        k_xvar_p<<<(NVAR + B - 1) / B, B, 0, stream>>>(var_c, var_x, deg_var, Wv, bv,
                                                       Xs64, NVAR);
        k_gq_con<<<(4 * NCON + B - 1) / B, B, 0, stream>>>(csrC, start_con, deg_con, Xs64,
                                                           W2, b2, hs64, NCON);
        k_gq_final<<<NFQ, B, 0, stream>>>(csrV, start_var, deg_var, hs64, W2, b2,
                                          Wo1, bo1, Wo2, bo2, Wo3, bo3, partials, NVAR);
        k_out<<<1, B, 0, stream>>>(partials, NFQ, out);
        return;
    }

    // ---- fallback: unpadded layout, thread-per-node gathers ----
    off = 0;
    const int NF = (NVAR + B - 1) / B;
    int2*          fcsrV     = (int2*)walloc((size_t)ne * 8);
    int2*          fcsrC     = (int2*)walloc((size_t)ne * 8);
    int2*          fbuck     = (int2*)walloc((size_t)ne * 8);
    unsigned int*  fbhist    = (unsigned int*)walloc((size_t)scanN * 4);
    unsigned int*  fscanned  = (unsigned int*)walloc((size_t)scanN * 4);
    unsigned int*  fdeg_var  = (unsigned int*)walloc((size_t)NVAR * 4);
    unsigned int*  fstart_var= (unsigned int*)walloc((size_t)NVAR * 4);
    unsigned int*  fdeg_con  = (unsigned int*)walloc((size_t)NCON * 4);
    unsigned int*  fstart_con= (unsigned int*)walloc((size_t)NCON * 4);
    unsigned int*  fbsum     = (unsigned int*)walloc(4096);
    unsigned int*  fbscan    = (unsigned int*)walloc(4096);
    unsigned int*  fbdummy   = (unsigned int*)walloc(256);
    double*        fpart     = (double*)walloc((size_t)NF * 8 + 64);
    float* fXs     = (float*)fbuck;                                   // 40 MB overlay
    float* fhs_con = (float*)((char*)fbuck + (size_t)NVAR * HFE * 4); // 20 MB overlay

    kA_hist<<<nblkA, B, 0, stream>>>(e_src, fbhist, ne, 10, nblkA);
    k_scan_blocks<<<NBs, B, 0, stream>>>(fbhist, fscanned, fbsum, scanN);
    k_scan_blocks<<<1,   B, 0, stream>>>(fbsum, fbscan, fbdummy, NBs);
    k_scan_add   <<<NBs, B, 0, stream>>>(fscanned, fbscan, scanN);
    kA_scat<<<nblkA, B, 0, stream>>>(e_src, e_dst, e_w, fscanned, fbuck, ne, 10, nblkA);
    kB<<<BKV, B, 0, stream>>>(fbuck, fscanned, fdeg_var, fstart_var, fcsrV, NVAR, 10, nblkA);
    kA_hist<<<nblkA, B, 0, stream>>>(e_dst, fbhist, ne, 9, nblkA);
    k_scan_blocks<<<NBs, B, 0, stream>>>(fbhist, fscanned, fbsum, scanN);
    k_scan_blocks<<<1,   B, 0, stream>>>(fbsum, fbscan, fbdummy, NBs);
    k_scan_add   <<<NBs, B, 0, stream>>>(fscanned, fbscan, scanN);
    kA_scat<<<nblkA, B, 0, stream>>>(e_dst, e_src, e_w, fscanned, fbuck, ne, 9, nblkA);
    kB<<<BKC, B, 0, stream>>>(fbuck, fscanned, fdeg_con, fstart_con, fcsrC, NCON, 9, nblkA);
    k_xvar<<<(NVAR + B - 1) / B, B, 0, stream>>>(var_c, var_x, fdeg_var, Wv, bv, fXs, NVAR);
    k_gather_con<<<(NCON + B - 1) / B, B, 0, stream>>>(fcsrC, fstart_con, fdeg_con, fXs,
                                                       W2, b2, fhs_con, NCON);
    k_gather_final<<<NF, B, 0, stream>>>(fcsrV, fstart_var, fdeg_var, fhs_con, W2, b2,
                                         Wo1, bo1, Wo2, bo2, Wo3, bo3, fpart, NVAR);
    k_out<<<1, B, 0, stream>>>(fpart, NF, out);
}

// Round 9
// 735.951 us; speedup vs baseline: 1.4003x; 1.4003x over previous
//
#include <hip/hip_runtime.h>

#define NVAR 1000000
#define NCON 500000
#define HFE 10
#define EPB 8192     // edges per pass-A block
#define KB_CAP 8704  // kB staging capacity (bucket avg 8192, sd ~90 -> 5.7 sigma)

// ============================================================================
// Radix (atomic-free) CSR build; all global traffic sequential via LDS staging
// ============================================================================

__global__ __launch_bounds__(256) void kA_hist(const int* __restrict__ keys,
                                               unsigned int* __restrict__ bhist,
                                               int ne, int shift, int nblk) {
    __shared__ unsigned int h[1024];
    int tid = threadIdx.x, b = blockIdx.x;
    for (int t = tid; t < 1024; t += 256) h[t] = 0;
    __syncthreads();
    int beg = b * EPB, end = min(ne, beg + EPB);
    for (int e = beg + tid; e < end; e += 256) atomicAdd(&h[keys[e] >> shift], 1u);
    __syncthreads();
    for (int t = tid; t < 1024; t += 256) bhist[(size_t)t * nblk + b] = h[t];
}

// stage payload in LDS at ranked slot; emit slots in order -> coalesced writes.
// All global reads sequential (keys read twice; 2nd is L2-hot).
__global__ __launch_bounds__(256) void kA_scat(const int* __restrict__ keys,
                                               const int* __restrict__ vals,
                                               const float* __restrict__ w,
                                               const unsigned int* __restrict__ scanned,
                                               int2* __restrict__ bucketed,
                                               int ne, int shift, int nblk) {
    __shared__ unsigned int h[1024];    // histogram, then rank cursor
    __shared__ unsigned int lb[1024];   // local exclusive base
    __shared__ unsigned int gb[1024];   // global segment base
    __shared__ unsigned int sc[256];
    __shared__ int2 stage[EPB];         // 64 KB payload staging
    int tid = threadIdx.x, b = blockIdx.x;
    for (int t = tid; t < 1024; t += 256) {
        h[t] = 0;
        gb[t] = scanned[(size_t)t * nblk + b];
    }
    __syncthreads();
    int beg = b * EPB, end = min(ne, beg + EPB), cnt = end - beg;
    // phase 0: local histogram (sequential int4 reads)
    int cnt4 = cnt >> 2;
    const int4* keys4 = (const int4*)(keys + beg);
    for (int i = tid; i < cnt4; i += 256) {
        int4 k = keys4[i];
        atomicAdd(&h[k.x >> shift], 1u);
        atomicAdd(&h[k.y >> shift], 1u);
        atomicAdd(&h[k.z >> shift], 1u);
        atomicAdd(&h[k.w >> shift], 1u);
    }
    for (int i = cnt4 * 4 + tid; i < cnt; i += 256) atomicAdd(&h[keys[beg + i] >> shift], 1u);
    __syncthreads();
    // exclusive scan h -> lb
    unsigned v0, v1, v2, v3;
    int q = tid * 4;
    v0 = h[q]; v1 = h[q + 1]; v2 = h[q + 2]; v3 = h[q + 3];
    sc[tid] = v0 + v1 + v2 + v3;
    __syncthreads();
    for (int dd = 1; dd < 256; dd <<= 1) {
        unsigned add = (tid >= dd) ? sc[tid - dd] : 0u;
        __syncthreads();
        sc[tid] += add;
        __syncthreads();
    }
    unsigned ex = (tid == 0) ? 0u : sc[tid - 1];
    lb[q]     = ex;
    lb[q + 1] = ex + v0;
    lb[q + 2] = ex + v0 + v1;
    lb[q + 3] = ex + v0 + v1 + v2;
    __syncthreads();
    // reset rank cursors
    for (int t = tid; t < 1024; t += 256) h[t] = 0;
    __syncthreads();
    // phase 1: sequential read, stage payload at ranked LDS slot
    unsigned mask = (1u << shift) - 1u;
    const int4* vals4 = (const int4*)(vals + beg);
    const float4* w4 = (const float4*)(w + beg);
    for (int i = tid; i < cnt4; i += 256) {
        int4 k = vals4 ? keys4[i] : keys4[i];   // keep simple; same load
        int4 v = vals4[i];
        float4 ww = w4[i];
        {
            unsigned bkt = (unsigned)k.x >> shift;
            unsigned r = atomicAdd(&h[bkt], 1u);
            stage[lb[bkt] + r] = make_int2(__float_as_int(ww.x),
                                           (v.x << shift) | (unsigned)(k.x & (int)mask));
        }
        {
            unsigned bkt = (unsigned)k.y >> shift;
            unsigned r = atomicAdd(&h[bkt], 1u);
            stage[lb[bkt] + r] = make_int2(__float_as_int(ww.y),
                                           (v.y << shift) | (unsigned)(k.y & (int)mask));
        }
        {
            unsigned bkt = (unsigned)k.z >> shift;
            unsigned r = atomicAdd(&h[bkt], 1u);
            stage[lb[bkt] + r] = make_int2(__float_as_int(ww.z),
                                           (v.z << shift) | (unsigned)(k.z & (int)mask));
        }
        {
            unsigned bkt = (unsigned)k.w >> shift;
            unsigned r = atomicAdd(&h[bkt], 1u);
            stage[lb[bkt] + r] = make_int2(__float_as_int(ww.w),
                                           (v.w << shift) | (unsigned)(k.w & (int)mask));
        }
    }
    for (int i = cnt4 * 4 + tid; i < cnt; i += 256) {
        int k = keys[beg + i];
        unsigned bkt = (unsigned)k >> shift;
        unsigned r = atomicAdd(&h[bkt], 1u);
        stage[lb[bkt] + r] = make_int2(__float_as_int(w[beg + i]),
                                       (vals[beg + i] << shift) | (unsigned)(k & (int)mask));
    }
    __syncthreads();
    // phase 2: emit slots in order; bucket via binary search over lb (monotone)
    for (int i = tid; i < cnt; i += 256) {
        unsigned bb = 0;
#pragma unroll
        for (int step = 512; step > 0; step >>= 1) {
            unsigned cand = bb + step;
            if (cand < 1024 && lb[cand] <= (unsigned)i) bb = cand;
        }
        bucketed[gb[bb] + ((unsigned)i - lb[bb])] = stage[i];
    }
}

// per-bucket: histogram -> deg/start; rank-stage in LDS; sequential csr emit
__global__ __launch_bounds__(256) void kB(const int2* __restrict__ bucketed,
                                          const unsigned int* __restrict__ scanned,
                                          unsigned int* __restrict__ deg,
                                          unsigned int* __restrict__ start,
                                          int2* __restrict__ csr,
                                          int nnodes, int shift, int nblk) {
    __shared__ unsigned int h[1024], s[1024], cr[1024], sc[256];
    __shared__ int2 stage[KB_CAP];
    const int W = 1 << shift;
    const unsigned mask = (unsigned)(W - 1);
    int d = blockIdx.x, tid = threadIdx.x;
    unsigned base = scanned[(size_t)d * nblk];
    unsigned next = scanned[(size_t)(d + 1) * nblk];
    int bsz = (int)(next - base);
    for (int t = tid; t < W; t += 256) { h[t] = 0; cr[t] = 0; }
    __syncthreads();
    for (int i = tid; i < bsz; i += 256)
        atomicAdd(&h[(unsigned)bucketed[base + i].y & mask], 1u);  // LDS atomic
    __syncthreads();
    // exclusive scan h[0..W) -> s
    unsigned v0 = 0, v1 = 0, v2 = 0, v3 = 0;
    int q = tid * 4;
    if (q < W) { v0 = h[q]; v1 = h[q + 1]; v2 = h[q + 2]; v3 = h[q + 3]; }
    sc[tid] = v0 + v1 + v2 + v3;
    __syncthreads();
    for (int dd = 1; dd < 256; dd <<= 1) {
        unsigned add = (tid >= dd) ? sc[tid - dd] : 0u;
        __syncthreads();
        sc[tid] += add;
        __syncthreads();
    }
    unsigned e = (tid == 0) ? 0u : sc[tid - 1];
    if (q < W) {
        s[q]     = e;
        s[q + 1] = e + v0;
        s[q + 2] = e + v0 + v1;
        s[q + 3] = e + v0 + v1 + v2;
    }
    __syncthreads();
    int lo = d << shift;
    for (int t = tid; t < W; t += 256) {
        int node = lo + t;
        if (node < nnodes) { deg[node] = h[t]; start[node] = base + s[t]; }
    }
    __syncthreads();
    if (bsz <= KB_CAP) {
        // rank-stage: sequential read (L2-hot), transformed payload to ranked slot
        for (int i = tid; i < bsz; i += 256) {
            int2 p = bucketed[base + i];
            unsigned low = (unsigned)p.y & mask;
            unsigned r = atomicAdd(&cr[low], 1u);
            stage[s[low] + r] = make_int2(p.y >> shift, p.x);   // {neighbor, w}
        }
        __syncthreads();
        // emit: fully coalesced sequential write
        for (int j = tid; j < bsz; j += 256) csr[base + j] = stage[j];
    } else {
        // safety fallback (statistically unreachable)
        for (int i = tid; i < bsz; i += 256) {
            int2 p = bucketed[base + i];
            unsigned low = (unsigned)p.y & mask;
            unsigned pos = base + s[low] + atomicAdd(&cr[low], 1u);
            csr[pos] = make_int2(p.y >> shift, p.x);
        }
    }
}

__global__ __launch_bounds__(256) void k_scan_blocks(const unsigned int* __restrict__ in,
                                                     unsigned int* __restrict__ out,
                                                     unsigned int* __restrict__ bsum,
                                                     int n) {
    __shared__ unsigned int sT[256];
    int base = blockIdx.x * 1024 + threadIdx.x * 4;
    unsigned int v0 = 0, v1 = 0, v2 = 0, v3 = 0;
    if (base + 3 < n) {
        uint4 u = *(const uint4*)(in + base);
        v0 = u.x; v1 = u.y; v2 = u.z; v3 = u.w;
    } else {
        if (base     < n) v0 = in[base];
        if (base + 1 < n) v1 = in[base + 1];
        if (base + 2 < n) v2 = in[base + 2];
        if (base + 3 < n) v3 = in[base + 3];
    }
    sT[threadIdx.x] = v0 + v1 + v2 + v3;
    __syncthreads();
    for (int d = 1; d < 256; d <<= 1) {
        unsigned int add = (threadIdx.x >= (unsigned)d) ? sT[threadIdx.x - d] : 0u;
        __syncthreads();
        sT[threadIdx.x] += add;
        __syncthreads();
    }
    unsigned int excl = (threadIdx.x == 0) ? 0u : sT[threadIdx.x - 1];
    if (base     < n) out[base]     = excl;
    if (base + 1 < n) out[base + 1] = excl + v0;
    if (base + 2 < n) out[base + 2] = excl + v0 + v1;
    if (base + 3 < n) out[base + 3] = excl + v0 + v1 + v2;
    if (threadIdx.x == 255 && bsum) bsum[blockIdx.x] = sT[255];
}

__global__ __launch_bounds__(256) void k_scan_add(unsigned int* __restrict__ data,
                                                  const unsigned int* __restrict__ bscan,
                                                  int n) {
    int base = blockIdx.x * 1024 + threadIdx.x * 4;
    unsigned int add = bscan[blockIdx.x];
    if (base + 3 < n) {
        uint4 u = *(const uint4*)(data + base);
        u.x += add; u.y += add; u.z += add; u.w += add;
        *(uint4*)(data + base) = u;
    } else {
        if (base     < n) data[base]     += add;
        if (base + 1 < n) data[base + 1] += add;
        if (base + 2 < n) data[base + 2] += add;
        if (base + 3 < n) data[base + 3] += add;
    }
}

__global__ __launch_bounds__(256) void k_out(const double* __restrict__ partials, int np,
                                             float* __restrict__ out) {
    __shared__ double red[256];
    double a = 0.0;
    for (int i = threadIdx.x; i < np; i += blockDim.x) a += partials[i];
    red[threadIdx.x] = a;
    __syncthreads();
    for (int off = 128; off > 0; off >>= 1) {
        if (threadIdx.x < off) red[threadIdx.x] += red[threadIdx.x + off];
        __syncthreads();
    }
    if (threadIdx.x == 0) out[0] = (float)(red[0] / (double)NVAR);
}

// ============================================================================
// PADDED node pipeline: 64 B feature rows, quad-per-node gathers, 4-edge unroll
// ============================================================================

__global__ __launch_bounds__(256) void k_xvar_p(const float* __restrict__ var_c,
                                                const float* __restrict__ var_x,
                                                const unsigned int* __restrict__ deg_var,
                                                const float* __restrict__ Wv,
                                                const float* __restrict__ bv,
                                                float* __restrict__ Xs, int n) {
    int i = blockIdx.x * blockDim.x + threadIdx.x;
    if (i >= n) return;
    float c = var_c[i], x = var_x[i];
    float rs = rsqrtf(fmaxf((float)deg_var[i], 1.0f));
    float o[16];
#pragma unroll
    for (int j = 0; j < HFE; j++) {
        float t = fmaf(c, Wv[j], fmaf(x, Wv[HFE + j], bv[j]));
        o[j] = fmaxf(t, 0.0f) * rs;
    }
#pragma unroll
    for (int j = HFE; j < 16; j++) o[j] = 0.0f;
    float4* dst4 = (float4*)(Xs + (size_t)i * 16);
#pragma unroll
    for (int j = 0; j < 4; j++)
        dst4[j] = make_float4(o[4 * j], o[4 * j + 1], o[4 * j + 2], o[4 * j + 3]);
}

__global__ __launch_bounds__(256) void k_gq_con(const int2* __restrict__ csr,
                                                const unsigned int* __restrict__ start,
                                                const unsigned int* __restrict__ deg,
                                                const float* __restrict__ feat,  // [N][16]
                                                const float* __restrict__ W2,
                                                const float* __restrict__ b2,
                                                float* __restrict__ hs, int n) { // [n][16]
    __shared__ float sW[100], sb[10];
    for (int t = threadIdx.x; t < 100; t += blockDim.x) sW[t] = W2[t];
    if (threadIdx.x < 10) sb[threadIdx.x] = b2[threadIdx.x];
    __syncthreads();
    int t = blockIdx.x * blockDim.x + threadIdx.x;
    int quad = t >> 2, lane = t & 3;
    if (quad >= n) return;
    unsigned beg = start[quad], cnt = deg[quad], end = beg + cnt;
    float4 acc = make_float4(0.f, 0.f, 0.f, 0.f);
    unsigned p = beg;
    for (; p + 4 <= end; p += 4) {
        int2 e0 = csr[p];
        int2 e1 = csr[p + 1];
        int2 e2 = csr[p + 2];
        int2 e3 = csr[p + 3];
        float4 v0 = *(const float4*)(feat + (size_t)e0.x * 16 + lane * 4);
        float4 v1 = *(const float4*)(feat + (size_t)e1.x * 16 + lane * 4);
        float4 v2 = *(const float4*)(feat + (size_t)e2.x * 16 + lane * 4);
        float4 v3 = *(const float4*)(feat + (size_t)e3.x * 16 + lane * 4);
        float w0 = __int_as_float(e0.y), w1 = __int_as_float(e1.y);
        float w2 = __int_as_float(e2.y), w3 = __int_as_float(e3.y);
        acc.x = fmaf(w0, v0.x, acc.x); acc.y = fmaf(w0, v0.y, acc.y);
        acc.z = fmaf(w0, v0.z, acc.z); acc.w = fmaf(w0, v0.w, acc.w);
        acc.x = fmaf(w1, v1.x, acc.x); acc.y = fmaf(w1, v1.y, acc.y);
        acc.z = fmaf(w1, v1.z, acc.z); acc.w = fmaf(w1, v1.w, acc.w);
        acc.x = fmaf(w2, v2.x, acc.x); acc.y = fmaf(w2, v2.y, acc.y);
        acc.z = fmaf(w2, v2.z, acc.z); acc.w = fmaf(w2, v2.w, acc.w);
        acc.x = fmaf(w3, v3.x, acc.x); acc.y = fmaf(w3, v3.y, acc.y);
        acc.z = fmaf(w3, v3.z, acc.z); acc.w = fmaf(w3, v3.w, acc.w);
    }
    for (; p < end; ++p) {
        int2 e = csr[p];
        float we = __int_as_float(e.y);
        float4 v = *(const float4*)(feat + (size_t)e.x * 16 + lane * 4);
        acc.x = fmaf(we, v.x, acc.x);
        acc.y = fmaf(we, v.y, acc.y);
        acc.z = fmaf(we, v.z, acc.z);
        acc.w = fmaf(we, v.w, acc.w);
    }
    float rs = rsqrtf(fmaxf((float)cnt, 1.0f));
    float a[10];
    a[0] = __shfl(acc.x, 0, 4); a[1] = __shfl(acc.y, 0, 4);
    a[2] = __shfl(acc.z, 0, 4); a[3] = __shfl(acc.w, 0, 4);
    a[4] = __shfl(acc.x, 1, 4); a[5] = __shfl(acc.y, 1, 4);
    a[6] = __shfl(acc.z, 1, 4); a[7] = __shfl(acc.w, 1, 4);
    a[8] = __shfl(acc.x, 2, 4); a[9] = __shfl(acc.y, 2, 4);
#pragma unroll
    for (int j = 0; j < 10; j++) a[j] *= rs;
    float o[12];
#pragma unroll
    for (int k = 0; k < 10; k++) {
        float s2 = sb[k];
#pragma unroll
        for (int j = 0; j < 10; j++) s2 = fmaf(a[j], sW[j * 10 + k], s2);
        o[k] = fmaxf(s2, 0.0f) * rs;   // relu + prescale for conv2
    }
    o[10] = 0.0f; o[11] = 0.0f;
    float4 wv = (lane < 3) ? make_float4(o[lane * 4], o[lane * 4 + 1],
                                         o[lane * 4 + 2], o[lane * 4 + 3])
                           : make_float4(0.f, 0.f, 0.f, 0.f);
    *(float4*)(hs + (size_t)quad * 16 + lane * 4) = wv;
}

__global__ __launch_bounds__(256) void k_gq_final(const int2* __restrict__ csr,
                                                  const unsigned int* __restrict__ start,
                                                  const unsigned int* __restrict__ deg,
                                                  const float* __restrict__ feat, // [NCON][16]
                                                  const float* __restrict__ W2,
                                                  const float* __restrict__ b2,
                                                  const float* __restrict__ Wo1,
                                                  const float* __restrict__ bo1,
                                                  const float* __restrict__ Wo2,
                                                  const float* __restrict__ bo2,
                                                  const float* __restrict__ Wo3,
                                                  const float* __restrict__ bo3,
                                                  double* __restrict__ partials, int n) {
    __shared__ float sW2[100], sb2[10], sWo1[100], sbo1[10], sWo2[100], sbo2[10], sWo3[10], sbo3;
    for (int t = threadIdx.x; t < 100; t += blockDim.x) {
        sW2[t] = W2[t]; sWo1[t] = Wo1[t]; sWo2[t] = Wo2[t];
    }
    if (threadIdx.x < 10) {
        sb2[threadIdx.x]  = b2[threadIdx.x];
        sbo1[threadIdx.x] = bo1[threadIdx.x];
        sbo2[threadIdx.x] = bo2[threadIdx.x];
        sWo3[threadIdx.x] = Wo3[threadIdx.x];
    }
    if (threadIdx.x == 0) sbo3 = bo3[0];
    __syncthreads();

    int t = blockIdx.x * blockDim.x + threadIdx.x;
    int quad = t >> 2, lane = t & 3;
    double accd = 0.0;
    if (quad < n) {
        unsigned beg = start[quad], cnt = deg[quad], end = beg + cnt;
        float4 acc = make_float4(0.f, 0.f, 0.f, 0.f);
        unsigned p = beg;
        for (; p + 4 <= end; p += 4) {
            int2 e0 = csr[p];
            int2 e1 = csr[p + 1];
            int2 e2 = csr[p + 2];
            int2 e3 = csr[p + 3];
            float4 v0 = *(const float4*)(feat + (size_t)e0.x * 16 + lane * 4);
            float4 v1 = *(const float4*)(feat + (size_t)e1.x * 16 + lane * 4);
            float4 v2 = *(const float4*)(feat + (size_t)e2.x * 16 + lane * 4);
            float4 v3 = *(const float4*)(feat + (size_t)e3.x * 16 + lane * 4);
            float w0 = __int_as_float(e0.y), w1 = __int_as_float(e1.y);
            float w2 = __int_as_float(e2.y), w3 = __int_as_float(e3.y);
            acc.x = fmaf(w0, v0.x, acc.x); acc.y = fmaf(w0, v0.y, acc.y);
            acc.z = fmaf(w0, v0.z, acc.z); acc.w = fmaf(w0, v0.w, acc.w);
            acc.x = fmaf(w1, v1.x, acc.x); acc.y = fmaf(w1, v1.y, acc.y);
            acc.z = fmaf(w1, v1.z, acc.z); acc.w = fmaf(w1, v1.w, acc.w);
            acc.x = fmaf(w2, v2.x, acc.x); acc.y = fmaf(w2, v2.y, acc.y);
            acc.z = fmaf(w2, v2.z, acc.z); acc.w = fmaf(w2, v2.w, acc.w);
            acc.x = fmaf(w3, v3.x, acc.x); acc.y = fmaf(w3, v3.y, acc.y);
            acc.z = fmaf(w3, v3.z, acc.z); acc.w = fmaf(w3, v3.w, acc.w);
        }
        for (; p < end; ++p) {
            int2 e = csr[p];
            float we = __int_as_float(e.y);
            float4 v = *(const float4*)(feat + (size_t)e.x * 16 + lane * 4);
            acc.x = fmaf(we, v.x, acc.x);
            acc.y = fmaf(we, v.y, acc.y);
            acc.z = fmaf(we, v.z, acc.z);
            acc.w = fmaf(we, v.w, acc.w);
        }
        float rs = rsqrtf(fmaxf((float)cnt, 1.0f));
        float a[10];
        a[0] = __shfl(acc.x, 0, 4); a[1] = __shfl(acc.y, 0, 4);
        a[2] = __shfl(acc.z, 0, 4); a[3] = __shfl(acc.w, 0, 4);
        a[4] = __shfl(acc.x, 1, 4); a[5] = __shfl(acc.y, 1, 4);
        a[6] = __shfl(acc.z, 1, 4); a[7] = __shfl(acc.w, 1, 4);
        a[8] = __shfl(acc.x, 2, 4); a[9] = __shfl(acc.y, 2, 4);
#pragma unroll
        for (int j = 0; j < 10; j++) a[j] *= rs;
        float h[10], z[10];
#pragma unroll
        for (int k = 0; k < 10; k++) {
            float s2 = sb2[k];
#pragma unroll
            for (int j = 0; j < 10; j++) s2 = fmaf(a[j], sW2[j * 10 + k], s2);
            h[k] = fmaxf(s2, 0.0f);
        }
#pragma unroll
        for (int k = 0; k < 10; k++) {
            float s2 = sbo1[k];
#pragma unroll
            for (int j = 0; j < 10; j++) s2 = fmaf(h[j], sWo1[j * 10 + k], s2);
            z[k] = fmaxf(s2, 0.0f);
        }
        float t3 = sbo3;
#pragma unroll
        for (int k = 0; k < 10; k++) {
            float s2 = sbo2[k];
#pragma unroll
            for (int j = 0; j < 10; j++) s2 = fmaf(z[j], sWo2[j * 10 + k], s2);
            s2 = fmaxf(s2, 0.0f);
            t3 = fmaf(s2, sWo3[k], t3);
        }
        if (lane == 0) accd = (double)t3;   // lanes 1-3 hold identical t3
    }

    __shared__ double red[256];
    red[threadIdx.x] = accd;
    __syncthreads();
    for (int off = blockDim.x / 2; off > 0; off >>= 1) {
        if (threadIdx.x < off) red[threadIdx.x] += red[threadIdx.x + off];
        __syncthreads();
    }
    if (threadIdx.x == 0) partials[blockIdx.x] = red[0];
}

// ============================================================================
// FALLBACK node kernels (unpadded): only used if ws too small for padded path
// ============================================================================

__global__ __launch_bounds__(256) void k_xvar(const float* __restrict__ var_c,
                                              const float* __restrict__ var_x,
                                              const unsigned int* __restrict__ deg_var,
                                              const float* __restrict__ Wv,
                                              const float* __restrict__ bv,
                                              float* __restrict__ Xs, int n) {
    int i = blockIdx.x * blockDim.x + threadIdx.x;
    if (i >= n) return;
    float c = var_c[i], x = var_x[i];
    float rs = rsqrtf(fmaxf((float)deg_var[i], 1.0f));
    float o[HFE];
#pragma unroll
    for (int j = 0; j < HFE; j++) {
        float t = fmaf(c, Wv[j], fmaf(x, Wv[HFE + j], bv[j]));
        o[j] = fmaxf(t, 0.0f) * rs;
    }
    float2* dst2 = (float2*)(Xs + (size_t)i * HFE);
#pragma unroll
    for (int j = 0; j < 5; j++) dst2[j] = make_float2(o[2 * j], o[2 * j + 1]);
}

__global__ __launch_bounds__(256) void k_gather_con(const int2* __restrict__ csr,
                                                    const unsigned int* __restrict__ start,
                                                    const unsigned int* __restrict__ deg,
                                                    const float* __restrict__ feat,
                                                    const float* __restrict__ W2,
                                                    const float* __restrict__ b2,
                                                    float* __restrict__ hs, int n) {
    __shared__ float sW[100], sb[10];
    for (int t = threadIdx.x; t < 100; t += blockDim.x) sW[t] = W2[t];
    if (threadIdx.x < 10) sb[threadIdx.x] = b2[threadIdx.x];
    __syncthreads();
    int i = blockIdx.x * blockDim.x + threadIdx.x;
    if (i >= n) return;
    unsigned int beg = start[i], cnt = deg[i], end = beg + cnt;
    float acc[HFE];
#pragma unroll
    for (int j = 0; j < HFE; j++) acc[j] = 0.0f;
    for (unsigned int p = beg; p < end; ++p) {
        int2 t = csr[p];
        float we = __int_as_float(t.y);
        const float2* row = (const float2*)(feat + (size_t)t.x * HFE);
#pragma unroll
        for (int j = 0; j < 5; j++) {
            float2 v = row[j];
            acc[2 * j]     = fmaf(we, v.x, acc[2 * j]);
            acc[2 * j + 1] = fmaf(we, v.y, acc[2 * j + 1]);
        }
    }
    float rs = rsqrtf(fmaxf((float)cnt, 1.0f));
#pragma unroll
    for (int j = 0; j < HFE; j++) acc[j] *= rs;
    float o[HFE];
#pragma unroll
    for (int k = 0; k < HFE; k++) {
        float t = sb[k];
#pragma unroll
        for (int j = 0; j < HFE; j++) t = fmaf(acc[j], sW[j * HFE + k], t);
        o[k] = fmaxf(t, 0.0f) * rs;
    }
    float2* dst2 = (float2*)(hs + (size_t)i * HFE);
#pragma unroll
    for (int j = 0; j < 5; j++) dst2[j] = make_float2(o[2 * j], o[2 * j + 1]);
}

__global__ __launch_bounds__(256) void k_gather_final(const int2* __restrict__ csr,
                                                      const unsigned int* __restrict__ start,
                                                      const unsigned int* __restrict__ deg,
                                                      const float* __restrict__ feat,
                                                      const float* __restrict__ W2,
                                                      const float* __restrict__ b2,
                                                      const float* __restrict__ Wo1,
                                                      const float* __restrict__ bo1,
                                                      const float* __restrict__ Wo2,
                                                      const float* __restrict__ bo2,
                                                      const float* __restrict__ Wo3,
                                                      const float* __restrict__ bo3,
                                                      double* __restrict__ partials, int n) {
    __shared__ float sW2[100], sb2[10], sWo1[100], sbo1[10], sWo2[100], sbo2[10], sWo3[10], sbo3;
    for (int t = threadIdx.x; t < 100; t += blockDim.x) {
        sW2[t] = W2[t]; sWo1[t] = Wo1[t]; sWo2[t] = Wo2[t];
    }
    if (threadIdx.x < 10) {
        sb2[threadIdx.x]  = b2[threadIdx.x];
        sbo1[threadIdx.x] = bo1[threadIdx.x];
        sbo2[threadIdx.x] = bo2[threadIdx.x];
        sWo3[threadIdx.x] = Wo3[threadIdx.x];
    }
    if (threadIdx.x == 0) sbo3 = bo3[0];
    __syncthreads();

    double accd = 0.0;
    int i = blockIdx.x * blockDim.x + threadIdx.x;
    if (i < n) {
        unsigned int beg = start[i], cnt = deg[i], end = beg + cnt;
        float acc[HFE];
#pragma unroll
        for (int j = 0; j < HFE; j++) acc[j] = 0.0f;
        for (unsigned int p = beg; p < end; ++p) {
            int2 t = csr[p];
            float we = __int_as_float(t.y);
            const float2* row = (const float2*)(feat + (size_t)t.x * HFE);
#pragma unroll
            for (int j = 0; j < 5; j++) {
                float2 v = row[j];
                acc[2 * j]     = fmaf(we, v.x, acc[2 * j]);
                acc[2 * j + 1] = fmaf(we, v.y, acc[2 * j + 1]);
            }
        }
        float rs = rsqrtf(fmaxf((float)cnt, 1.0f));
#pragma unroll
        for (int j = 0; j < HFE; j++) acc[j] *= rs;
        float h[HFE], z[HFE];
#pragma unroll
        for (int k = 0; k < HFE; k++) {
            float t = sb2[k];
#pragma unroll
            for (int j = 0; j < HFE; j++) t = fmaf(acc[j], sW2[j * HFE + k], t);
            h[k] = fmaxf(t, 0.0f);
        }
#pragma unroll
        for (int k = 0; k < HFE; k++) {
            float t = sbo1[k];
#pragma unroll
            for (int j = 0; j < HFE; j++) t = fmaf(h[j], sWo1[j * HFE + k], t);
            z[k] = fmaxf(t, 0.0f);
        }
        float t3 = sbo3;
#pragma unroll
        for (int k = 0; k < HFE; k++) {
            float t = sbo2[k];
#pragma unroll
            for (int j = 0; j < HFE; j++) t = fmaf(z[j], sWo2[j * HFE + k], t);
            t = fmaxf(t, 0.0f);
            t3 = fmaf(t, sWo3[k], t3);
        }
        accd = (double)t3;
    }

    __shared__ double red[256];
    red[threadIdx.x] = accd;
    __syncthreads();
    for (int off = blockDim.x / 2; off > 0; off >>= 1) {
        if (threadIdx.x < off) red[threadIdx.x] += red[threadIdx.x + off];
        __syncthreads();
    }
    if (threadIdx.x == 0) partials[blockIdx.x] = red[0];
}

// ============================================================================
// Launch
// ============================================================================

extern "C" void kernel_launch(void* const* d_in, const int* in_sizes, int n_in,
                              void* d_out, int out_size, void* d_ws, size_t ws_size,
                              hipStream_t stream) {
    const float* var_c  = (const float*)d_in[0];
    const float* var_x  = (const float*)d_in[1];
    const int*   e_src  = (const int*)d_in[3];
    const int*   e_dst  = (const int*)d_in[4];
    const float* e_w    = (const float*)d_in[5];
    const float* Wv     = (const float*)d_in[6];
    const float* bv     = (const float*)d_in[7];
    const float* W2     = (const float*)d_in[12];
    const float* b2     = (const float*)d_in[13];
    const float* Wo1    = (const float*)d_in[14];
    const float* bo1    = (const float*)d_in[15];
    const float* Wo2    = (const float*)d_in[16];
    const float* bo2    = (const float*)d_in[17];
    const float* Wo3    = (const float*)d_in[18];
    const float* bo3    = (const float*)d_in[19];
    float* out = (float*)d_out;
    const int ne = in_sizes[3];
    (void)n_in; (void)out_size;

    const int B = 256;
    const int nblkA = (ne + EPB - 1) / EPB;     // 977
    const int scanN = 1024 * nblkA;
    const int NBs   = (scanN + 1023) / 1024;
    const int BKV   = (NVAR + 1023) >> 10;      // shift 10
    const int BKC   = (NCON + 511) >> 9;        // shift 9

    char* ws = (char*)d_ws;
    size_t off = 0;
    auto walloc = [&](size_t bytes) {
        void* p = ws + off;
        off = (off + bytes + 255) & ~(size_t)255;
        return p;
    };

    // ---- padded-path layout ----
    const int NFQ = (4 * NVAR + B - 1) / B;     // 15625 partials (quad final)
    int2*          csrV     = (int2*)walloc((size_t)ne * 8);             // 64 MB
    int2*          csrC     = (int2*)walloc((size_t)ne * 8);             // 64 MB
    int2*          bucketed = (int2*)walloc((size_t)ne * 8);             // 64 MB
    unsigned int*  bhist    = (unsigned int*)walloc((size_t)scanN * 4);  //  4 MB
    unsigned int*  scanned  = (unsigned int*)walloc((size_t)scanN * 4);  //  4 MB
    unsigned int*  deg_var  = (unsigned int*)walloc((size_t)NVAR * 4);
    unsigned int*  start_var= (unsigned int*)walloc((size_t)NVAR * 4);
    unsigned int*  deg_con  = (unsigned int*)walloc((size_t)NCON * 4);
    unsigned int*  start_con= (unsigned int*)walloc((size_t)NCON * 4);
    unsigned int*  bsum     = (unsigned int*)walloc(4096);
    unsigned int*  bscan    = (unsigned int*)walloc(4096);
    unsigned int*  bdummy   = (unsigned int*)walloc(256);
    double*        partials = (double*)walloc((size_t)NFQ * 8 + 64);
    float*         hs64     = (float*)walloc((size_t)NCON * 16 * 4);     // 32 MB
    size_t need_padded = off;
    float* Xs64 = (float*)bucketed;    // 64 MB overlay: bucketed dead after sortC

    if (ws_size >= need_padded) {
        // ---- sort V (key = src, shift 10) ----
        kA_hist<<<nblkA, B, 0, stream>>>(e_src, bhist, ne, 10, nblkA);
        k_scan_blocks<<<NBs, B, 0, stream>>>(bhist, scanned, bsum, scanN);
        k_scan_blocks<<<1,   B, 0, stream>>>(bsum, bscan, bdummy, NBs);
        k_scan_add   <<<NBs, B, 0, stream>>>(scanned, bscan, scanN);
        kA_scat<<<nblkA, B, 0, stream>>>(e_src, e_dst, e_w, scanned, bucketed, ne, 10, nblkA);
        kB<<<BKV, B, 0, stream>>>(bucketed, scanned, deg_var, start_var, csrV, NVAR, 10, nblkA);
        // ---- sort C (key = dst, shift 9) ----
        kA_hist<<<nblkA, B, 0, stream>>>(e_dst, bhist, ne, 9, nblkA);
        k_scan_blocks<<<NBs, B, 0, stream>>>(bhist, scanned, bsum, scanN);
        k_scan_blocks<<<1,   B, 0, stream>>>(bsum, bscan, bdummy, NBs);
        k_scan_add   <<<NBs, B, 0, stream>>>(scanned, bscan, scanN);
        kA_scat<<<nblkA, B, 0, stream>>>(e_dst, e_src, e_w, scanned, bucketed, ne, 9, nblkA);
        kB<<<BKC, B, 0, stream>>>(bucketed, scanned, deg_con, start_con, csrC, NCON, 9, nblkA);
        // ---- node pipeline (padded rows, quad gathers, unrolled) ----
        k_xvar_p<<<(NVAR + B - 1) / B, B, 0, stream>>>(var_c, var_x, deg_var, Wv, bv,
                                                       Xs64, NVAR);
        k_gq_con<<<(4 * NCON + B - 1) / B, B, 0, stream>>>(csrC, start_con, deg_con, Xs64,
                                                           W2, b2, hs64, NCON);
        k_gq_final<<<NFQ, B, 0, stream>>>(csrV, start_var, deg_var, hs64, W2, b2,
                                          Wo1, bo1, Wo2, bo2, Wo3, bo3, partials, NVAR);
        k_out<<<1, B, 0, stream>>>(partials, NFQ, out);
        return;
    }

    // ---- fallback: unpadded layout, thread-per-node gathers ----
    off = 0;
    const int NF = (NVAR + B - 1) / B;
    int2*          fcsrV     = (int2*)walloc((size_t)ne * 8);
    int2*          fcsrC     = (int2*)walloc((size_t)ne * 8);
    int2*          fbuck     = (int2*)walloc((size_t)ne * 8);
    unsigned int*  fbhist    = (unsigned int*)walloc((size_t)scanN * 4);
    unsigned int*  fscanned  = (unsigned int*)walloc((size_t)scanN * 4);
    unsigned int*  fdeg_var  = (unsigned int*)walloc((size_t)NVAR * 4);
    unsigned int*  fstart_var= (unsigned int*)walloc((size_t)NVAR * 4);
    unsigned int*  fdeg_con  = (unsigned int*)walloc((size_t)NCON * 4);
    unsigned int*  fstart_con= (unsigned int*)walloc((size_t)NCON * 4);
    unsigned int*  fbsum     = (unsigned int*)walloc(4096);
    unsigned int*  fbscan    = (unsigned int*)walloc(4096);
    unsigned int*  fbdummy   = (unsigned int*)walloc(256);
    double*        fpart     = (double*)walloc((size_t)NF * 8 + 64);
    float* fXs     = (float*)fbuck;                                   // 40 MB overlay
    float* fhs_con = (float*)((char*)fbuck + (size_t)NVAR * HFE * 4); // 20 MB overlay

    kA_hist<<<nblkA, B, 0, stream>>>(e_src, fbhist, ne, 10, nblkA);
    k_scan_blocks<<<NBs, B, 0, stream>>>(fbhist, fscanned, fbsum, scanN);
    k_scan_blocks<<<1,   B, 0, stream>>>(fbsum, fbscan, fbdummy, NBs);
    k_scan_add   <<<NBs, B, 0, stream>>>(fscanned, fbscan, scanN);
    kA_scat<<<nblkA, B, 0, stream>>>(e_src, e_dst, e_w, fscanned, fbuck, ne, 10, nblkA);
    kB<<<BKV, B, 0, stream>>>(fbuck, fscanned, fdeg_var, fstart_var, fcsrV, NVAR, 10, nblkA);
    kA_hist<<<nblkA, B, 0, stream>>>(e_dst, fbhist, ne, 9, nblkA);
    k_scan_blocks<<<NBs, B, 0, stream>>>(fbhist, fscanned, fbsum, scanN);
    k_scan_blocks<<<1,   B, 0, stream>>>(fbsum, fbscan, fbdummy, NBs);
    k_scan_add   <<<NBs, B, 0, stream>>>(fscanned, fbscan, scanN);
    kA_scat<<<nblkA, B, 0, stream>>>(e_dst, e_src, e_w, fscanned, fbuck, ne, 9, nblkA);
    kB<<<BKC, B, 0, stream>>>(fbuck, fscanned, fdeg_con, fstart_con, fcsrC, NCON, 9, nblkA);
    k_xvar<<<(NVAR + B - 1) / B, B, 0, stream>>>(var_c, var_x, fdeg_var, Wv, bv, fXs, NVAR);
    k_gather_con<<<(NCON + B - 1) / B, B, 0, stream>>>(fcsrC, fstart_con, fdeg_con, fXs,
                                                       W2, b2, fhs_con, NCON);
    k_gather_final<<<NF, B, 0, stream>>>(fcsrV, fstart_var, fdeg_var, fhs_con, W2, b2,
                                         Wo1, bo1, Wo2, bo2, Wo3, bo3, fpart, NVAR);
    k_out<<<1, B, 0, stream>>>(fpart, NF, out);
}